// Round 4
// baseline (586.153 us; speedup 1.0000x reference)
//
#include <hip/hip_runtime.h>
#include <hip/hip_bf16.h>

#define S_LEN 2048
#define HEADS 16
#define DIM 64
#define QBLK 64
#define KVBLK 64
#define NBH 64          // B*H
#define NTILES 32       // S_LEN / KVBLK
#define MBIAS 9.0f      // static log2-domain max bound (softmax shift-invariant)

typedef __attribute__((ext_vector_type(8))) short short8;
typedef __attribute__((ext_vector_type(4))) short short4v;
typedef __attribute__((ext_vector_type(4))) float f32x4;

__device__ __forceinline__ short f2bf(float f) {
    __hip_bfloat16 h = __float2bfloat16(f);
    return *reinterpret_cast<const short*>(&h);
}

// cheap round-to-nearest-even f32->bf16 (valid for finite positive values)
__device__ __forceinline__ short f2bf_rne(float f) {
    unsigned u = __float_as_uint(f);
    u += 0x7FFF + ((u >> 16) & 1);
    return (short)(u >> 16);
}

__device__ __forceinline__ void gl_lds16(const void* g, void* s) {
    __builtin_amdgcn_global_load_lds(
        (const __attribute__((address_space(1))) unsigned*)g,
        (__attribute__((address_space(3))) unsigned*)s, 16, 0, 0);
}

// select O[db][idx] with static register indexing (rule #20)
#define SELQ(dst, db, idx) do { dst = O[db][0];                      \
    if ((idx) == 1) dst = O[db][1];                                  \
    if ((idx) == 2) dst = O[db][2];                                  \
    if ((idx) == 3) dst = O[db][3]; } while (0)
#define ADDQ(db, idx, val) do {                                      \
    if ((idx) == 0) O[db][0] += (val);                               \
    if ((idx) == 1) O[db][1] += (val);                               \
    if ((idx) == 2) O[db][2] += (val);                               \
    if ((idx) == 3) O[db][3] += (val); } while (0)

// ---------------- prepass: K -> bf16, swizzled LDS image ----------------
// Kg layout: [bh][kv] rows of 128B, byte-in-row = (d*2) ^ ((kv&7)<<4)
__global__ __launch_bounds__(256)
void prep_k_kernel(const float* __restrict__ k_q, char* __restrict__ Kg)
{
    const int u  = blockIdx.x * 256 + threadIdx.x;
    const int c  = u & 7;
    const int kv = (u >> 3) & (S_LEN - 1);
    const int bh = u >> 14;
    const int b  = bh >> 4;
    const int h  = bh & 15;

    const float* src = k_q + ((size_t)b * S_LEN + kv) * (HEADS * DIM) + h * DIM + c * 8;
    float4 a = *reinterpret_cast<const float4*>(src);
    float4 d = *reinterpret_cast<const float4*>(src + 4);
    short8 f;
    f[0]=f2bf(a.x); f[1]=f2bf(a.y); f[2]=f2bf(a.z); f[3]=f2bf(a.w);
    f[4]=f2bf(d.x); f[5]=f2bf(d.y); f[6]=f2bf(d.z); f[7]=f2bf(d.w);
    char* dst = Kg + ((size_t)bh * S_LEN + kv) * 128 + ((c * 16) ^ ((kv & 7) << 4));
    *reinterpret_cast<short8*>(dst) = f;
}

// ---------------- prepass: V -> bf16 transposed, swizzled -----------------
// Vg layout: [bh][tile][d] rows of 128B (kv in row), byte = (kv*2) ^ ((d&7)<<4)
__global__ __launch_bounds__(256)
void prep_v_kernel(const float* __restrict__ v_q, char* __restrict__ Vg)
{
    __shared__ short Vt[64][72];
    const int tid  = threadIdx.x;
    const int tile = blockIdx.x;
    const int bh   = blockIdx.y;
    const int b    = bh >> 4;
    const int h    = bh & 15;
    const int kvbase = tile * KVBLK;

    {
        const int kv = tid >> 2;
        const int d0 = (tid & 3) * 16;
        const float* src = v_q + ((size_t)b * S_LEN + kvbase + kv) * (HEADS * DIM) + h * DIM + d0;
        #pragma unroll
        for (int g = 0; g < 4; ++g) {
            float4 v = *reinterpret_cast<const float4*>(src + g * 4);
            Vt[d0 + g * 4 + 0][kv] = f2bf(v.x);
            Vt[d0 + g * 4 + 1][kv] = f2bf(v.y);
            Vt[d0 + g * 4 + 2][kv] = f2bf(v.z);
            Vt[d0 + g * 4 + 3][kv] = f2bf(v.w);
        }
    }
    __syncthreads();
    {
        const int d = tid >> 2;
        const int c = tid & 3;
        short8 f0 = *reinterpret_cast<const short8*>(&Vt[d][c * 16]);
        short8 f1 = *reinterpret_cast<const short8*>(&Vt[d][c * 16 + 8]);
        char* base = Vg + (((size_t)bh * NTILES + tile) * 64 + d) * 128;
        const int s = (d & 7) << 4;
        *reinterpret_cast<short8*>(base + ((c * 32) ^ s))      = f0;
        *reinterpret_cast<short8*>(base + ((c * 32 + 16) ^ s)) = f1;
    }
}

// ------- main attention: waves split KV; P stays in registers -------------
__global__ __launch_bounds__(256)
void fa_fwd_pre(const float* __restrict__ q_q, const char* __restrict__ Kg,
                const char* __restrict__ Vg, const float* __restrict__ q_scale,
                const float* __restrict__ k_scale, const float* __restrict__ v_scale,
                float* __restrict__ out)
{
    __shared__ __attribute__((aligned(16))) char ldsbuf[32768];
    __shared__ float lsums[4][4][16];
    char* Klb = ldsbuf;            // [2][8192] K tiles
    char* Vlb = ldsbuf + 16384;    // [2][8192] V^T tiles

    const int tid = threadIdx.x;
    const int w   = tid >> 6;
    const int l   = tid & 63;
    const int l15 = l & 15;
    const int l4  = l >> 4;
    const int swz = (l15 & 7) << 4;

    const int qtile = (int)gridDim.x - 1 - (int)blockIdx.x;  // heavy first
    const int bh = blockIdx.y;
    const int b  = bh >> 4;
    const int h  = bh & 15;

    const int qbase = qtile * QBLK;
    const int sstride = HEADS * DIM;
    const size_t bh_off = ((size_t)b * S_LEN * HEADS + h) * DIM;

    const float c2 = q_scale[h] * k_scale[h] * 0.125f * 1.4426950408889634f;
    const float vs = v_scale[h];

    // ---- Q: all 64 block q-rows in registers as QK B-frags ----
    // B-frag: col=q=qg*16+l15, k = d = kc*32 + l4*8 + j
    short8 qf[4][2];
    #pragma unroll
    for (int qg = 0; qg < 4; ++qg) {
        const float* qp = q_q + bh_off + (size_t)(qbase + qg * 16 + l15) * sstride;
        #pragma unroll
        for (int kc = 0; kc < 2; ++kc) {
            const int d0 = kc * 32 + l4 * 8;
            float4 a = *reinterpret_cast<const float4*>(qp + d0);
            float4 c = *reinterpret_cast<const float4*>(qp + d0 + 4);
            short8 f;
            f[0]=f2bf(a.x*c2); f[1]=f2bf(a.y*c2); f[2]=f2bf(a.z*c2); f[3]=f2bf(a.w*c2);
            f[4]=f2bf(c.x*c2); f[5]=f2bf(c.y*c2); f[6]=f2bf(c.z*c2); f[7]=f2bf(c.w*c2);
            qf[qg][kc] = f;
        }
    }

    // O[db][qg]: col=q=qg*16+l15, row=d=db*16+l4*4+r  (per-wave partial over kv slice)
    f32x4 O[4][4];
    #pragma unroll
    for (int db = 0; db < 4; ++db)
        #pragma unroll
        for (int qg = 0; qg < 4; ++qg)
            O[db][qg] = (f32x4){0.f, 0.f, 0.f, 0.f};
    float lsum[4] = {0.f, 0.f, 0.f, 0.f};

    const int ntiles = qtile + 1;
    const size_t kg_bh = (size_t)bh * S_LEN * 128;
    const size_t vg_bh = (size_t)bh * NTILES * 8192;
    const int woff = w * 2048 + l * 16;

    auto STAGE = [&](int X, int t) {
        const char* ks   = Kg + kg_bh + (size_t)t * KVBLK * 128 + woff;
        const char* vsrc = Vg + vg_bh + (size_t)t * 8192 + woff;
        gl_lds16(ks,          Klb + X * 8192 + w * 2048);
        gl_lds16(ks + 1024,   Klb + X * 8192 + w * 2048 + 1024);
        gl_lds16(vsrc,        Vlb + X * 8192 + w * 2048);
        gl_lds16(vsrc + 1024, Vlb + X * 8192 + w * 2048 + 1024);
    };

    STAGE(0, 0);

    const int krow = w * 16 + l15;          // kv row this lane loads for A-frag

    for (int t = 0; t < ntiles; ++t) {
        const int cur = t & 1;
        __syncthreads();                     // drains my stage loads + all arrive
        if (t + 1 < ntiles) STAGE(cur ^ 1, t + 1);

        const char* KB = Klb + cur * 8192;
        const char* VB = Vlb + cur * 8192;

        // K A-frags: row=kv(slice), k=d
        short8 kf0 = *reinterpret_cast<const short8*>(KB + krow * 128 + ((l4 * 16) ^ swz));
        short8 kf1 = *reinterpret_cast<const short8*>(KB + krow * 128 + ((64 + l4 * 16) ^ swz));
        // V^T A-frags: row=d, k=kv(slice): 4 consecutive kv at w*16+l4*4
        short4v vf[4];
        #pragma unroll
        for (int db = 0; db < 4; ++db)
            vf[db] = *reinterpret_cast<const short4v*>(
                VB + (db * 16 + l15) * 128 + ((w * 32 + l4 * 8) ^ swz));

        // ---- QK^T: sc[qg] col=q, row=kv_loc=l4*4+r ----
        f32x4 sc[4];
        #pragma unroll
        for (int qg = 0; qg < 4; ++qg) {
            f32x4 acc = {0.f, 0.f, 0.f, 0.f};
            acc = __builtin_amdgcn_mfma_f32_16x16x32_bf16(kf0, qf[qg][0], acc, 0, 0, 0);
            acc = __builtin_amdgcn_mfma_f32_16x16x32_bf16(kf1, qf[qg][1], acc, 0, 0, 0);
            sc[qg] = acc;
        }

        // ---- softmax (static max) + pack + PV, all lane-local ----
        const bool needMask = (t == ntiles - 1);
        const int kvg = t * KVBLK + w * 16 + l4 * 4;
        #pragma unroll
        for (int qg = 0; qg < 4; ++qg) {
            float s0 = sc[qg][0], s1 = sc[qg][1], s2 = sc[qg][2], s3 = sc[qg][3];
            if (needMask) {
                const int qv = qbase + qg * 16 + l15;
                if (kvg + 0 > qv) s0 = -1e30f;
                if (kvg + 1 > qv) s1 = -1e30f;
                if (kvg + 2 > qv) s2 = -1e30f;
                if (kvg + 3 > qv) s3 = -1e30f;
            }
            const float e0 = exp2f(s0 - MBIAS);
            const float e1 = exp2f(s1 - MBIAS);
            const float e2 = exp2f(s2 - MBIAS);
            const float e3 = exp2f(s3 - MBIAS);
            lsum[qg] += (e0 + e1) + (e2 + e3);
            short4v pb;
            pb[0] = f2bf_rne(e0); pb[1] = f2bf_rne(e1);
            pb[2] = f2bf_rne(e2); pb[3] = f2bf_rne(e3);
            // PV: O[d][q] += V^T[d][kv] * P[kv][q], k=16
            #pragma unroll
            for (int db = 0; db < 4; ++db)
                O[db][qg] = __builtin_amdgcn_mfma_f32_16x16x16bf16_1k(
                    vf[db], pb, O[db][qg], 0, 0, 0);
        }
    }

    // ---- epilogue: cross-wave O / lsum reduction, normalize, store ----
    __syncthreads();                          // last tile reads done

    float* red = (float*)ldsbuf;              // 8192 floats

    // round 1: wave w sends its qg=w^2 quarter
    {
        const int tgt = w ^ 2;
        float* dst = red + tgt * 1024 + l * 16;
        #pragma unroll
        for (int db = 0; db < 4; ++db) {
            f32x4 v; SELQ(v, db, tgt);
            *reinterpret_cast<f32x4*>(dst + db * 4) = v;
        }
    }
    // lsum: within-wave reduce over l4 groups, publish per-wave slice sums
    #pragma unroll
    for (int qg = 0; qg < 4; ++qg) {
        lsum[qg] += __shfl_xor(lsum[qg], 16);
        lsum[qg] += __shfl_xor(lsum[qg], 32);
    }
    if (l < 16) {
        #pragma unroll
        for (int qg = 0; qg < 4; ++qg) lsums[w][qg][l15] = lsum[qg];
    }
    __syncthreads();
    // round 1 add: my qg=w quarter += wave w^2's contribution
    {
        const float* src = red + w * 1024 + l * 16;
        #pragma unroll
        for (int db = 0; db < 4; ++db) {
            f32x4 v = *reinterpret_cast<const f32x4*>(src + db * 4);
            ADDQ(db, w, v);
        }
    }
    __syncthreads();
    // round 2: send unreduced quarters qg=w^1 (slot0 of target) and qg=w^3 (slot1)
    {
        const int t1 = w ^ 1;
        float* d1 = red + (t1 * 2 + 0) * 1024 + l * 16;
        #pragma unroll
        for (int db = 0; db < 4; ++db) {
            f32x4 v; SELQ(v, db, t1);
            *reinterpret_cast<f32x4*>(d1 + db * 4) = v;
        }
        const int t3 = w ^ 3;
        float* d3 = red + (t3 * 2 + 1) * 1024 + l * 16;
        #pragma unroll
        for (int db = 0; db < 4; ++db) {
            f32x4 v; SELQ(v, db, t3);
            *reinterpret_cast<f32x4*>(d3 + db * 4) = v;
        }
    }
    __syncthreads();
    // round 2 add + normalize + store (wave w owns q rows qbase+w*16..+15)
    {
        const float* s0 = red + (w * 2 + 0) * 1024 + l * 16;
        const float* s1 = red + (w * 2 + 1) * 1024 + l * 16;
        const float denom = lsums[0][w][l15] + lsums[1][w][l15] +
                            lsums[2][w][l15] + lsums[3][w][l15];
        const float inv = vs / denom;
        const int q = qbase + w * 16 + l15;
        float* op = out + bh_off + (size_t)q * sstride;
        #pragma unroll
        for (int db = 0; db < 4; ++db) {
            f32x4 v0 = *reinterpret_cast<const f32x4*>(s0 + db * 4);
            f32x4 v1 = *reinterpret_cast<const f32x4*>(s1 + db * 4);
            f32x4 mine; SELQ(mine, db, w);
            float4 o;
            o.x = (mine[0] + v0[0] + v1[0]) * inv;
            o.y = (mine[1] + v0[1] + v1[1]) * inv;
            o.z = (mine[2] + v0[2] + v1[2]) * inv;
            o.w = (mine[3] + v0[3] + v1[3]) * inv;
            *reinterpret_cast<float4*>(op + db * 16 + l4 * 4) = o;
        }
    }
}

// ---------------- fallback (round-1 kernel, used if ws too small) ---------
__global__ __launch_bounds__(256)
void fa_fwd_fallback(const float* __restrict__ q_q, const float* __restrict__ k_q,
                     const float* __restrict__ v_q, const float* __restrict__ q_scale,
                     const float* __restrict__ k_scale, const float* __restrict__ v_scale,
                     float* __restrict__ out)
{
    __shared__ char lds[8192 + 8192 + 4 * 16 * 144];
    char* Kl = lds;
    char* Vl = lds + 8192;
    char* Pl = lds + 16384;

    const int tid = threadIdx.x;
    const int w   = tid >> 6;
    const int l   = tid & 63;
    const int l15 = l & 15;
    const int l4  = l >> 4;

    const int qtile = (int)gridDim.x - 1 - (int)blockIdx.x;
    const int bh = blockIdx.y;
    const int b  = bh >> 4;
    const int h  = bh & 15;

    const int qbase = qtile * QBLK;
    const int sstride = HEADS * DIM;
    const size_t bh_off = ((size_t)b * S_LEN * HEADS + h) * DIM;

    const float c2 = q_scale[h] * k_scale[h] * 0.125f * 1.4426950408889634f;
    const float vs = v_scale[h];

    short8 qf[2];
    const int w_qmin = qbase + w * 16;
    {
        const float* qp = q_q + bh_off + (size_t)(w_qmin + l15) * sstride;
        #pragma unroll
        for (int kc = 0; kc < 2; ++kc) {
            const int d0 = kc * 32 + l4 * 8;
            float4 a = *reinterpret_cast<const float4*>(qp + d0);
            float4 c = *reinterpret_cast<const float4*>(qp + d0 + 4);
            short8 f;
            f[0]=f2bf(a.x*c2); f[1]=f2bf(a.y*c2); f[2]=f2bf(a.z*c2); f[3]=f2bf(a.w*c2);
            f[4]=f2bf(c.x*c2); f[5]=f2bf(c.y*c2); f[6]=f2bf(c.z*c2); f[7]=f2bf(c.w*c2);
            qf[kc] = f;
        }
    }

    f32x4 O[4] = {{0.f,0.f,0.f,0.f},{0.f,0.f,0.f,0.f},{0.f,0.f,0.f,0.f},{0.f,0.f,0.f,0.f}};
    float m2[4], lsum[4];
    #pragma unroll
    for (int r = 0; r < 4; ++r) { m2[r] = -1e30f; lsum[r] = 0.f; }

    const int kv_end = qbase + QBLK;

    for (int kvbase = 0; kvbase < kv_end; kvbase += KVBLK) {
        __syncthreads();
        {
            const float* kp = k_q + bh_off + (size_t)kvbase * sstride;
            #pragma unroll
            for (int i = 0; i < 4; ++i) {
                const int f4i = tid + i * 256;
                const int row  = f4i >> 4;
                const int col4 = (f4i & 15) * 4;
                float4 v = *reinterpret_cast<const float4*>(kp + (size_t)row * sstride + col4);
                uint2 pk;
                pk.x = (unsigned)(unsigned short)f2bf(v.x) | ((unsigned)(unsigned short)f2bf(v.y) << 16);
                pk.y = (unsigned)(unsigned short)f2bf(v.z) | ((unsigned)(unsigned short)f2bf(v.w) << 16);
                const int byte = row * 128 + ((col4 * 2) ^ ((row & 7) << 4));
                *reinterpret_cast<uint2*>(&Kl[byte]) = pk;
            }
        }
        {
            const float* vp = v_q + bh_off + (size_t)kvbase * sstride;
            #pragma unroll
            for (int g = 0; g < 2; ++g) {
                const int kv0 = w * 16 + g * 8;
                short8 f;
                #pragma unroll
                for (int j = 0; j < 8; ++j)
                    f[j] = f2bf(vp[(size_t)(kv0 + j) * sstride + l]);
                const int byte = l * 128 + ((kv0 * 2) ^ ((l & 7) << 4));
                *reinterpret_cast<short8*>(&Vl[byte]) = f;
            }
        }
        __syncthreads();

        const bool needMask = (kvbase + KVBLK - 1 > w_qmin);
        f32x4 sc[4];
        #pragma unroll
        for (int cb = 0; cb < 4; ++cb) {
            f32x4 acc = {0.f, 0.f, 0.f, 0.f};
            #pragma unroll
            for (int kc = 0; kc < 2; ++kc) {
                const int row  = cb * 16 + l15;
                const int colb = (kc * 32 + l4 * 8) * 2;
                short8 bf = *reinterpret_cast<const short8*>(
                    &Kl[row * 128 + (colb ^ ((row & 7) << 4))]);
                acc = __builtin_amdgcn_mfma_f32_16x16x32_bf16(qf[kc], bf, acc, 0, 0, 0);
            }
            sc[cb] = acc;
        }
        float p[4][4];
        #pragma unroll
        for (int cb = 0; cb < 4; ++cb) {
            const int kv = kvbase + cb * 16 + l15;
            #pragma unroll
            for (int r = 0; r < 4; ++r) {
                float s = sc[cb][r];
                if (needMask && kv > (w_qmin + l4 * 4 + r)) s = -1e30f;
                p[cb][r] = s;
            }
        }
        char* Pw = Pl + w * (16 * 144);
        #pragma unroll
        for (int r = 0; r < 4; ++r) {
            float t = fmaxf(fmaxf(p[0][r], p[1][r]), fmaxf(p[2][r], p[3][r]));
            t = fmaxf(t, __shfl_xor(t, 1));
            t = fmaxf(t, __shfl_xor(t, 2));
            t = fmaxf(t, __shfl_xor(t, 4));
            t = fmaxf(t, __shfl_xor(t, 8));
            const float mn   = fmaxf(m2[r], t);
            const float corr = exp2f(m2[r] - mn);
            m2[r] = mn;
            lsum[r] *= corr;
            #pragma unroll
            for (int db = 0; db < 4; ++db) O[db][r] *= corr;
            float ps = 0.f;
            #pragma unroll
            for (int cb = 0; cb < 4; ++cb) {
                const float e = exp2f(p[cb][r] - mn);
                p[cb][r] = e;
                ps += e;
            }
            lsum[r] += ps;
            const int prow = l4 * 4 + r;
            #pragma unroll
            for (int cb = 0; cb < 4; ++cb)
                *reinterpret_cast<short*>(&Pw[prow * 144 + (cb * 16 + l15) * 2]) =
                    f2bf(p[cb][r]);
        }
        #pragma unroll
        for (int kc = 0; kc < 2; ++kc) {
            short8 pf = *reinterpret_cast<const short8*>(
                &Pw[l15 * 144 + (kc * 32 + l4 * 8) * 2]);
            #pragma unroll
            for (int db = 0; db < 4; ++db) {
                const int row  = db * 16 + l15;
                const int colb = (kc * 32 + l4 * 8) * 2;
                short8 vf = *reinterpret_cast<const short8*>(
                    &Vl[row * 128 + (colb ^ ((row & 7) << 4))]);
                O[db] = __builtin_amdgcn_mfma_f32_16x16x32_bf16(pf, vf, O[db], 0, 0, 0);
            }
        }
    }

    #pragma unroll
    for (int r = 0; r < 4; ++r) {
        float t = lsum[r];
        t += __shfl_xor(t, 1);
        t += __shfl_xor(t, 2);
        t += __shfl_xor(t, 4);
        t += __shfl_xor(t, 8);
        const float inv = vs / t;
        const int q = w_qmin + l4 * 4 + r;
        float* op = out + bh_off + (size_t)q * sstride;
        #pragma unroll
        for (int db = 0; db < 4; ++db)
            op[db * 16 + l15] = O[db][r] * inv;
    }
}

extern "C" void kernel_launch(void* const* d_in, const int* in_sizes, int n_in,
                              void* d_out, int out_size, void* d_ws, size_t ws_size,
                              hipStream_t stream) {
    const float* q_q     = (const float*)d_in[0];
    const float* k_q     = (const float*)d_in[1];
    const float* v_q     = (const float*)d_in[2];
    const float* q_scale = (const float*)d_in[3];
    const float* k_scale = (const float*)d_in[4];
    const float* v_scale = (const float*)d_in[5];
    float* out = (float*)d_out;

    const size_t kbytes = (size_t)NBH * S_LEN * 128;   // 16.78 MB
    const size_t need   = kbytes * 2;

    if (ws_size >= need) {
        char* Kg = (char*)d_ws;
        char* Vg = Kg + kbytes;
        prep_k_kernel<<<dim3(4096), dim3(256), 0, stream>>>(k_q, Kg);
        prep_v_kernel<<<dim3(NTILES, NBH), dim3(256), 0, stream>>>(v_q, Vg);
        fa_fwd_pre<<<dim3(NTILES, NBH), dim3(256), 0, stream>>>(
            q_q, Kg, Vg, q_scale, k_scale, v_scale, out);
    } else {
        fa_fwd_fallback<<<dim3(NTILES, NBH), dim3(256), 0, stream>>>(
            q_q, k_q, v_q, q_scale, k_scale, v_scale, out);
    }
}

// Round 5
// 142.108 us; speedup vs baseline: 4.1247x; 4.1247x over previous
//
#include <hip/hip_runtime.h>
#include <hip/hip_bf16.h>

#define S_LEN 2048
#define HEADS 16
#define DIM 64
#define QBLK 64          // fallback kernel q-tile
#define QBLK2 128        // main kernel q-tile (8 waves x 16 q rows)
#define KVBLK 64
#define NBH 64           // B*H
#define NTILES 32        // S_LEN / KVBLK
#define MBIAS 9.0f       // static log2-domain max bound (softmax shift-invariant)

typedef __attribute__((ext_vector_type(8))) short short8;
typedef __attribute__((ext_vector_type(4))) short short4v;
typedef __attribute__((ext_vector_type(4))) float f32x4;

__device__ __forceinline__ short f2bf(float f) {
    __hip_bfloat16 h = __float2bfloat16(f);
    return *reinterpret_cast<const short*>(&h);
}

// cheap round-to-nearest-even f32->bf16 (valid for finite positive values)
__device__ __forceinline__ short f2bf_rne(float f) {
    unsigned u = __float_as_uint(f);
    u += 0x7FFF + ((u >> 16) & 1);
    return (short)(u >> 16);
}

__device__ __forceinline__ void gl_lds16(const void* g, void* s) {
    __builtin_amdgcn_global_load_lds(
        (const __attribute__((address_space(1))) unsigned*)g,
        (__attribute__((address_space(3))) unsigned*)s, 16, 0, 0);
}

// ---------------- prepass: K -> bf16, swizzled LDS image ----------------
// Kg layout: [bh][kv] rows of 128B, byte-in-row = (d*2) ^ ((kv&7)<<4)
__global__ __launch_bounds__(256)
void prep_k_kernel(const float* __restrict__ k_q, char* __restrict__ Kg)
{
    const int u  = blockIdx.x * 256 + threadIdx.x;
    const int c  = u & 7;
    const int kv = (u >> 3) & (S_LEN - 1);
    const int bh = u >> 14;
    const int b  = bh >> 4;
    const int h  = bh & 15;

    const float* src = k_q + ((size_t)b * S_LEN + kv) * (HEADS * DIM) + h * DIM + c * 8;
    float4 a = *reinterpret_cast<const float4*>(src);
    float4 d = *reinterpret_cast<const float4*>(src + 4);
    short8 f;
    f[0]=f2bf(a.x); f[1]=f2bf(a.y); f[2]=f2bf(a.z); f[3]=f2bf(a.w);
    f[4]=f2bf(d.x); f[5]=f2bf(d.y); f[6]=f2bf(d.z); f[7]=f2bf(d.w);
    char* dst = Kg + ((size_t)bh * S_LEN + kv) * 128 + ((c * 16) ^ ((kv & 7) << 4));
    *reinterpret_cast<short8*>(dst) = f;
}

// ---------------- prepass: V -> bf16 transposed, swizzled -----------------
// Vg layout: [bh][tile][d] rows of 128B (kv in row), byte = (kv*2) ^ ((d&7)<<4)
__global__ __launch_bounds__(256)
void prep_v_kernel(const float* __restrict__ v_q, char* __restrict__ Vg)
{
    __shared__ short Vt[64][72];
    const int tid  = threadIdx.x;
    const int tile = blockIdx.x;
    const int bh   = blockIdx.y;
    const int b    = bh >> 4;
    const int h    = bh & 15;
    const int kvbase = tile * KVBLK;

    {
        const int kv = tid >> 2;
        const int d0 = (tid & 3) * 16;
        const float* src = v_q + ((size_t)b * S_LEN + kvbase + kv) * (HEADS * DIM) + h * DIM + d0;
        #pragma unroll
        for (int g = 0; g < 4; ++g) {
            float4 v = *reinterpret_cast<const float4*>(src + g * 4);
            Vt[d0 + g * 4 + 0][kv] = f2bf(v.x);
            Vt[d0 + g * 4 + 1][kv] = f2bf(v.y);
            Vt[d0 + g * 4 + 2][kv] = f2bf(v.z);
            Vt[d0 + g * 4 + 3][kv] = f2bf(v.w);
        }
    }
    __syncthreads();
    {
        const int d = tid >> 2;
        const int c = tid & 3;
        short8 f0 = *reinterpret_cast<const short8*>(&Vt[d][c * 16]);
        short8 f1 = *reinterpret_cast<const short8*>(&Vt[d][c * 16 + 8]);
        char* base = Vg + (((size_t)bh * NTILES + tile) * 64 + d) * 128;
        const int s = (d & 7) << 4;
        *reinterpret_cast<short8*>(base + ((c * 32) ^ s))      = f0;
        *reinterpret_cast<short8*>(base + ((c * 32 + 16) ^ s)) = f1;
    }
}

// ------- main attention: 8 waves split 128 q rows; P stays in registers ---
__global__ __launch_bounds__(512)
void fa_fwd_pre(const float* __restrict__ q_q, const char* __restrict__ Kg,
                const char* __restrict__ Vg, const float* __restrict__ q_scale,
                const float* __restrict__ k_scale, const float* __restrict__ v_scale,
                float* __restrict__ out)
{
    __shared__ __attribute__((aligned(16))) char Klb[2][8192];
    __shared__ __attribute__((aligned(16))) char Vlb[2][8192];

    const int tid = threadIdx.x;
    const int w   = tid >> 6;          // 0..7
    const int l   = tid & 63;
    const int l15 = l & 15;
    const int l4  = l >> 4;
    const int swz = (l15 & 7) << 4;

    const int qtile = (int)gridDim.x - 1 - (int)blockIdx.x;  // heavy first
    const int bh = blockIdx.y;
    const int b  = bh >> 4;
    const int h  = bh & 15;

    const int qbase = qtile * QBLK2;
    const int sstride = HEADS * DIM;
    const size_t bh_off = ((size_t)b * S_LEN * HEADS + h) * DIM;

    const float c2 = q_scale[h] * k_scale[h] * 0.125f * 1.4426950408889634f;
    const float vs = v_scale[h];

    // Q fragments (B-operand): col=q=w_qmin+l15, k=d=kc*32+l4*8+j
    short8 qf0, qf1;
    const int w_qmin = qbase + w * 16;
    const int qv = w_qmin + l15;
    {
        const float* qp = q_q + bh_off + (size_t)qv * sstride;
        #pragma unroll
        for (int kc = 0; kc < 2; ++kc) {
            const int d0 = kc * 32 + l4 * 8;
            float4 a = *reinterpret_cast<const float4*>(qp + d0);
            float4 c = *reinterpret_cast<const float4*>(qp + d0 + 4);
            short8 f;
            f[0]=f2bf(a.x*c2); f[1]=f2bf(a.y*c2); f[2]=f2bf(a.z*c2); f[3]=f2bf(a.w*c2);
            f[4]=f2bf(c.x*c2); f[5]=f2bf(c.y*c2); f[6]=f2bf(c.z*c2); f[7]=f2bf(c.w*c2);
            if (kc == 0) qf0 = f; else qf1 = f;
        }
    }

    // O[db]: col=q=l15(+w_qmin), row=d=db*16+l4*4+r
    f32x4 O[4] = {{0.f,0.f,0.f,0.f},{0.f,0.f,0.f,0.f},{0.f,0.f,0.f,0.f},{0.f,0.f,0.f,0.f}};
    float lsum = 0.f;

    const int ntiles = 2 * qtile + 2;
    const size_t kg_bh = (size_t)bh * S_LEN * 128;
    const size_t vg_bh = (size_t)bh * NTILES * 8192;
    const int woff = w * 1024 + l * 16;

    auto STAGE = [&](int X, int t) {
        const char* ks   = Kg + kg_bh + (size_t)t * KVBLK * 128 + woff;
        const char* vsrc = Vg + vg_bh + (size_t)t * 8192 + woff;
        gl_lds16(ks,   &Klb[X][w * 1024]);
        gl_lds16(vsrc, &Vlb[X][w * 1024]);
    };

    STAGE(0, 0);

    for (int t = 0; t < ntiles; ++t) {
        const int cur = t & 1;
        __syncthreads();                 // drains vmcnt (stages done) + all arrive
        if (t + 1 < ntiles) STAGE(cur ^ 1, t + 1);

        const int kvbase = t * KVBLK;
        if (kvbase > w_qmin + 15) continue;   // fully masked for this wave

        const char* KB = Klb[cur];
        const char* VB = Vlb[cur];
        const bool needMask = (kvbase + KVBLK - 1 > w_qmin);

        #pragma unroll
        for (int cb = 0; cb < 4; ++cb) {
            // ---- QK^T for this 16-kv block (swapped: col=q, row=kv) ----
            const int row = cb * 16 + l15;
            short8 kf0 = *reinterpret_cast<const short8*>(
                KB + row * 128 + ((l4 * 16) ^ swz));
            short8 kf1 = *reinterpret_cast<const short8*>(
                KB + row * 128 + ((64 + l4 * 16) ^ swz));
            f32x4 acc = {0.f, 0.f, 0.f, 0.f};
            acc = __builtin_amdgcn_mfma_f32_16x16x32_bf16(kf0, qf0, acc, 0, 0, 0);
            acc = __builtin_amdgcn_mfma_f32_16x16x32_bf16(kf1, qf1, acc, 0, 0, 0);

            // ---- static-max softmax, lane-local ----
            float s0 = acc[0], s1 = acc[1], s2 = acc[2], s3 = acc[3];
            if (needMask) {
                const int kvg = kvbase + cb * 16 + l4 * 4;
                if (kvg + 0 > qv) s0 = -1e30f;
                if (kvg + 1 > qv) s1 = -1e30f;
                if (kvg + 2 > qv) s2 = -1e30f;
                if (kvg + 3 > qv) s3 = -1e30f;
            }
            const float e0 = exp2f(s0 - MBIAS);
            const float e1 = exp2f(s1 - MBIAS);
            const float e2 = exp2f(s2 - MBIAS);
            const float e3 = exp2f(s3 - MBIAS);
            lsum += (e0 + e1) + (e2 + e3);
            short4v pb;
            pb[0] = f2bf_rne(e0); pb[1] = f2bf_rne(e1);
            pb[2] = f2bf_rne(e2); pb[3] = f2bf_rne(e3);

            // ---- PV for this kv block: O[d][q] += V^T[d][kv] * P[kv][q] ----
            #pragma unroll
            for (int db = 0; db < 4; ++db) {
                const int vrow = db * 16 + l15;
                short4v vf = *reinterpret_cast<const short4v*>(
                    VB + vrow * 128 + ((cb * 32 + l4 * 8) ^ swz));
                O[db] = __builtin_amdgcn_mfma_f32_16x16x16bf16_1k(vf, pb, O[db], 0, 0, 0);
            }
        }
    }

    // ---- epilogue: reduce lsum across l4 groups, normalize, store ----
    lsum += __shfl_xor(lsum, 16);
    lsum += __shfl_xor(lsum, 32);
    const float inv = vs / lsum;
    float* op = out + bh_off + (size_t)qv * sstride;
    #pragma unroll
    for (int db = 0; db < 4; ++db) {
        float4 o;
        o.x = O[db][0] * inv; o.y = O[db][1] * inv;
        o.z = O[db][2] * inv; o.w = O[db][3] * inv;
        *reinterpret_cast<float4*>(op + db * 16 + l4 * 4) = o;
    }
}

// ---------------- fallback (round-1 kernel, used if ws too small) ---------
__global__ __launch_bounds__(256)
void fa_fwd_fallback(const float* __restrict__ q_q, const float* __restrict__ k_q,
                     const float* __restrict__ v_q, const float* __restrict__ q_scale,
                     const float* __restrict__ k_scale, const float* __restrict__ v_scale,
                     float* __restrict__ out)
{
    __shared__ char lds[8192 + 8192 + 4 * 16 * 144];
    char* Kl = lds;
    char* Vl = lds + 8192;
    char* Pl = lds + 16384;

    const int tid = threadIdx.x;
    const int w   = tid >> 6;
    const int l   = tid & 63;
    const int l15 = l & 15;
    const int l4  = l >> 4;

    const int qtile = (int)gridDim.x - 1 - (int)blockIdx.x;
    const int bh = blockIdx.y;
    const int b  = bh >> 4;
    const int h  = bh & 15;

    const int qbase = qtile * QBLK;
    const int sstride = HEADS * DIM;
    const size_t bh_off = ((size_t)b * S_LEN * HEADS + h) * DIM;

    const float c2 = q_scale[h] * k_scale[h] * 0.125f * 1.4426950408889634f;
    const float vs = v_scale[h];

    short8 qf[2];
    const int w_qmin = qbase + w * 16;
    {
        const float* qp = q_q + bh_off + (size_t)(w_qmin + l15) * sstride;
        #pragma unroll
        for (int kc = 0; kc < 2; ++kc) {
            const int d0 = kc * 32 + l4 * 8;
            float4 a = *reinterpret_cast<const float4*>(qp + d0);
            float4 c = *reinterpret_cast<const float4*>(qp + d0 + 4);
            short8 f;
            f[0]=f2bf(a.x*c2); f[1]=f2bf(a.y*c2); f[2]=f2bf(a.z*c2); f[3]=f2bf(a.w*c2);
            f[4]=f2bf(c.x*c2); f[5]=f2bf(c.y*c2); f[6]=f2bf(c.z*c2); f[7]=f2bf(c.w*c2);
            qf[kc] = f;
        }
    }

    f32x4 O[4] = {{0.f,0.f,0.f,0.f},{0.f,0.f,0.f,0.f},{0.f,0.f,0.f,0.f},{0.f,0.f,0.f,0.f}};
    float m2[4], lsum[4];
    #pragma unroll
    for (int r = 0; r < 4; ++r) { m2[r] = -1e30f; lsum[r] = 0.f; }

    const int kv_end = qbase + QBLK;

    for (int kvbase = 0; kvbase < kv_end; kvbase += KVBLK) {
        __syncthreads();
        {
            const float* kp = k_q + bh_off + (size_t)kvbase * sstride;
            #pragma unroll
            for (int i = 0; i < 4; ++i) {
                const int f4i = tid + i * 256;
                const int row  = f4i >> 4;
                const int col4 = (f4i & 15) * 4;
                float4 v = *reinterpret_cast<const float4*>(kp + (size_t)row * sstride + col4);
                uint2 pk;
                pk.x = (unsigned)(unsigned short)f2bf(v.x) | ((unsigned)(unsigned short)f2bf(v.y) << 16);
                pk.y = (unsigned)(unsigned short)f2bf(v.z) | ((unsigned)(unsigned short)f2bf(v.w) << 16);
                const int byte = row * 128 + ((col4 * 2) ^ ((row & 7) << 4));
                *reinterpret_cast<uint2*>(&Kl[byte]) = pk;
            }
        }
        {
            const float* vp = v_q + bh_off + (size_t)kvbase * sstride;
            #pragma unroll
            for (int g = 0; g < 2; ++g) {
                const int kv0 = w * 16 + g * 8;
                short8 f;
                #pragma unroll
                for (int j = 0; j < 8; ++j)
                    f[j] = f2bf(vp[(size_t)(kv0 + j) * sstride + l]);
                const int byte = l * 128 + ((kv0 * 2) ^ ((l & 7) << 4));
                *reinterpret_cast<short8*>(&Vl[byte]) = f;
            }
        }
        __syncthreads();

        const bool needMask = (kvbase + KVBLK - 1 > w_qmin);
        f32x4 sc[4];
        #pragma unroll
        for (int cb = 0; cb < 4; ++cb) {
            f32x4 acc = {0.f, 0.f, 0.f, 0.f};
            #pragma unroll
            for (int kc = 0; kc < 2; ++kc) {
                const int row  = cb * 16 + l15;
                const int colb = (kc * 32 + l4 * 8) * 2;
                short8 bf = *reinterpret_cast<const short8*>(
                    &Kl[row * 128 + (colb ^ ((row & 7) << 4))]);
                acc = __builtin_amdgcn_mfma_f32_16x16x32_bf16(qf[kc], bf, acc, 0, 0, 0);
            }
            sc[cb] = acc;
        }
        float p[4][4];
        #pragma unroll
        for (int cb = 0; cb < 4; ++cb) {
            const int kv = kvbase + cb * 16 + l15;
            #pragma unroll
            for (int r = 0; r < 4; ++r) {
                float s = sc[cb][r];
                if (needMask && kv > (w_qmin + l4 * 4 + r)) s = -1e30f;
                p[cb][r] = s;
            }
        }
        char* Pw = Pl + w * (16 * 144);
        #pragma unroll
        for (int r = 0; r < 4; ++r) {
            float t = fmaxf(fmaxf(p[0][r], p[1][r]), fmaxf(p[2][r], p[3][r]));
            t = fmaxf(t, __shfl_xor(t, 1));
            t = fmaxf(t, __shfl_xor(t, 2));
            t = fmaxf(t, __shfl_xor(t, 4));
            t = fmaxf(t, __shfl_xor(t, 8));
            const float mn   = fmaxf(m2[r], t);
            const float corr = exp2f(m2[r] - mn);
            m2[r] = mn;
            lsum[r] *= corr;
            #pragma unroll
            for (int db = 0; db < 4; ++db) O[db][r] *= corr;
            float ps = 0.f;
            #pragma unroll
            for (int cb = 0; cb < 4; ++cb) {
                const float e = exp2f(p[cb][r] - mn);
                p[cb][r] = e;
                ps += e;
            }
            lsum[r] += ps;
            const int prow = l4 * 4 + r;
            #pragma unroll
            for (int cb = 0; cb < 4; ++cb)
                *reinterpret_cast<short*>(&Pw[prow * 144 + (cb * 16 + l15) * 2]) =
                    f2bf(p[cb][r]);
        }
        #pragma unroll
        for (int kc = 0; kc < 2; ++kc) {
            short8 pf = *reinterpret_cast<const short8*>(
                &Pw[l15 * 144 + (kc * 32 + l4 * 8) * 2]);
            #pragma unroll
            for (int db = 0; db < 4; ++db) {
                const int row  = db * 16 + l15;
                const int colb = (kc * 32 + l4 * 8) * 2;
                short8 vf = *reinterpret_cast<const short8*>(
                    &Vl[row * 128 + (colb ^ ((row & 7) << 4))]);
                O[db] = __builtin_amdgcn_mfma_f32_16x16x32_bf16(pf, vf, O[db], 0, 0, 0);
            }
        }
    }

    #pragma unroll
    for (int r = 0; r < 4; ++r) {
        float t = lsum[r];
        t += __shfl_xor(t, 1);
        t += __shfl_xor(t, 2);
        t += __shfl_xor(t, 4);
        t += __shfl_xor(t, 8);
        const float inv = vs / t;
        const int q = w_qmin + l4 * 4 + r;
        float* op = out + bh_off + (size_t)q * sstride;
        #pragma unroll
        for (int db = 0; db < 4; ++db)
            op[db * 16 + l15] = O[db][r] * inv;
    }
}

extern "C" void kernel_launch(void* const* d_in, const int* in_sizes, int n_in,
                              void* d_out, int out_size, void* d_ws, size_t ws_size,
                              hipStream_t stream) {
    const float* q_q     = (const float*)d_in[0];
    const float* k_q     = (const float*)d_in[1];
    const float* v_q     = (const float*)d_in[2];
    const float* q_scale = (const float*)d_in[3];
    const float* k_scale = (const float*)d_in[4];
    const float* v_scale = (const float*)d_in[5];
    float* out = (float*)d_out;

    const size_t kbytes = (size_t)NBH * S_LEN * 128;   // 16.78 MB
    const size_t need   = kbytes * 2;

    if (ws_size >= need) {
        char* Kg = (char*)d_ws;
        char* Vg = Kg + kbytes;
        prep_k_kernel<<<dim3(4096), dim3(256), 0, stream>>>(k_q, Kg);
        prep_v_kernel<<<dim3(NTILES, NBH), dim3(256), 0, stream>>>(v_q, Vg);
        fa_fwd_pre<<<dim3(S_LEN / QBLK2, NBH), dim3(512), 0, stream>>>(
            q_q, Kg, Vg, q_scale, k_scale, v_scale, out);
    } else {
        fa_fwd_fallback<<<dim3(NTILES, NBH), dim3(256), 0, stream>>>(
            q_q, k_q, v_q, q_scale, k_scale, v_scale, out);
    }
}